// Round 1
// baseline (260.847 us; speedup 1.0000x reference)
//
#include <hip/hip_runtime.h>
#include <math.h>

#define HH 2048
#define WW 2048
#define NB1 256    // kernel-1 block: 4 waves, one row per wave
#define NT2 1024   // kernel-2 block: 16 waves, single workgroup

// ---------- wave reduction primitives ----------

__device__ __forceinline__ float wave_fmax(float v) {
#pragma unroll
  for (int m = 1; m < 64; m <<= 1) v = fmaxf(v, __shfl_xor(v, m, 64));
  return v;
}
__device__ __forceinline__ float wave_fsum(float v) {
#pragma unroll
  for (int m = 1; m < 64; m <<= 1) v += __shfl_xor(v, m, 64);
  return v;
}

// Block-wide max over 1024 threads (16 waves). 2 barriers.
__device__ float block_fmax16(float v) {
  __shared__ float s[16];
  v = wave_fmax(v);
  __syncthreads();                       // WAR guard across calls
  if ((threadIdx.x & 63) == 0) s[threadIdx.x >> 6] = v;
  __syncthreads();
  float m = s[0];
#pragma unroll
  for (int k = 1; k < 16; ++k) m = fmaxf(m, s[k]);
  return m;
}

// Block-wide sum of three values over 1024 threads. 2 barriers.
__device__ void block_fsum3_16(float& a, float& b, float& c) {
  __shared__ float sa[16], sb[16], sc[16];
  a = wave_fsum(a); b = wave_fsum(b); c = wave_fsum(c);
  __syncthreads();                       // WAR guard across calls
  if ((threadIdx.x & 63) == 0) {
    int w = threadIdx.x >> 6;
    sa[w] = a; sb[w] = b; sc[w] = c;
  }
  __syncthreads();
  float ra = 0.0f, rb = 0.0f, rc = 0.0f;
#pragma unroll
  for (int k = 0; k < 16; ++k) { ra += sa[k]; rb += sb[k]; rc += sc[k]; }
  a = ra; b = rb; c = rc;
}

// ---------- per-row softmax partial, computed by ONE wave, no barriers ----------
// Returns (M, z, sx) with z = sum(exp(100*v - M)), sx = sum(exp * col).
__device__ float4 wave_row_partial(const float* __restrict__ rowp) {
  const int lane = threadIdx.x & 63;
  const float4* r4 = (const float4*)rowp;
  float d[32];
  float m = -INFINITY;
#pragma unroll
  for (int p = 0; p < 8; ++p) {
    float4 v = r4[lane + 64 * p];
    d[4 * p + 0] = v.x * 100.0f;  // BETA
    d[4 * p + 1] = v.y * 100.0f;
    d[4 * p + 2] = v.z * 100.0f;
    d[4 * p + 3] = v.w * 100.0f;
    m = fmaxf(m, fmaxf(fmaxf(d[4 * p], d[4 * p + 1]), fmaxf(d[4 * p + 2], d[4 * p + 3])));
  }
  float M = wave_fmax(m);
  float z = 0.0f, sx = 0.0f;
#pragma unroll
  for (int p = 0; p < 8; ++p) {
    float c0 = (float)(4 * (lane + 64 * p));
#pragma unroll
    for (int k = 0; k < 4; ++k) {
      float e = expf(d[4 * p + k] - M);
      z += e;
      sx += e * (c0 + (float)k);
    }
  }
  z = wave_fsum(z);
  sx = wave_fsum(sx);
  return make_float4(M, z, sx, 0.0f);
}

// Merge per-row partials F[base+r], r in [s,e] (sy weight = r), with 1024 threads.
// Band length <= 2048 -> at most 2 rows per thread, cached in registers.
__device__ void merge_partials(const float4* __restrict__ F, int base, int s, int e,
                               float& M, float& Z, float& SX, float& SY) {
  int r0 = s + (int)threadIdx.x;
  int r1 = r0 + NT2;
  bool v0 = (r0 <= e), v1 = (r1 <= e);
  float4 p0 = v0 ? F[base + r0] : make_float4(-INFINITY, 0.0f, 0.0f, 0.0f);
  float4 p1 = v1 ? F[base + r1] : make_float4(-INFINITY, 0.0f, 0.0f, 0.0f);
  M = block_fmax16(fmaxf(p0.x, p1.x));
  float z = 0.0f, sx = 0.0f, sy = 0.0f;
  if (v0) {
    float w = expf(p0.x - M);
    z = w * p0.y; sx = w * p0.z; sy = w * p0.y * (float)r0;
  }
  if (v1) {
    float w = expf(p1.x - M);
    z += w * p1.y; sx += w * p1.z; sy += w * p1.y * (float)r1;
  }
  block_fsum3_16(z, sx, sy);
  Z = z; SX = sx; SY = sy;
}

// Analytic out-of-band complement (masked elements are exactly 0), then divide.
__device__ void finalize2(float M, float Z, float SX, float SY, int s, int e,
                          bool valid, float& ax, float& ay) {
  int nin = valid ? (e - s + 1) : 0;
  int nout = HH - nin;
  if (nout > 0) {
    float M2 = fmaxf(M, 0.0f);
    float wi = (M == M2) ? 1.0f : expf(M - M2);   // M=-inf -> 0
    float wo = (M2 == 0.0f) ? 1.0f : expf(-M2);   // underflows to 0 for typical M
    Z *= wi; SX *= wi; SY *= wi;
    float nout_e = (float)nout * (float)WW;                                  // exact
    float sox = (float)nout * 2096128.0f;                                    // nout*W(W-1)/2
    float sinr = valid ? (float)(((long)(s + e) * (e - s + 1)) / 2) : 0.0f;  // exact
    float soy = (2096128.0f - sinr) * 2048.0f;                               // exact
    Z  += wo * nout_e;
    SX += wo * sox;
    SY += wo * soy;
  }
  ax = SX / Z;
  ay = SY / Z;
}

// ---------- Kernel 1: per-row partials for ALL 11 channels ----------
// 22528 rows, one wave per row, grid sized exactly. Pure streaming read of
// the whole 184.5 MB input at HBM rate; partials (360 KB) land in L2/L3.
__global__ __launch_bounds__(NB1) void k_partials(const float* __restrict__ heat,
                                                  float4* __restrict__ F) {
  int gw = blockIdx.x * 4 + (int)(threadIdx.x >> 6);  // 0..22527 == ch*2048 + row
  float4 t = wave_row_partial(heat + (size_t)gw * WW);
  if ((threadIdx.x & 63) == 0) F[gw] = t;
}

// ---------- Kernel 2: the whole serial chain, one block ----------
// All merge inputs are tiny (<= 32 KB per merge) and cache-resident.
// All threads carry the identical scalar state; branches are block-uniform.
__global__ __launch_bounds__(NT2) void k_chain(const float4* __restrict__ F,
                                               float* __restrict__ out) {
  float o[22];
  float M, Z, SX, SY, ax, ay;

  // channels 9, 10: full-map soft-argmax
  merge_partials(F, 9 * HH, 0, HH - 1, M, Z, SX, SY);
  finalize2(M, Z, SX, SY, 0, HH - 1, true, ax, ay);
  o[18] = ax; o[19] = ay;
  merge_partials(F, 10 * HH, 0, HH - 1, M, Z, SX, SY);
  finalize2(M, Z, SX, SY, 0, HH - 1, true, ax, ay);
  o[20] = ax; o[21] = ay;

  float dis = o[21] - o[19], dsum = 0.0f, dnum = 0.0f;

#pragma unroll
  for (int i = 8; i >= 0; --i) {
    float y1 = o[2 * (i + 1) + 1];
    float y2 = o[2 * (i + 2) + 1];
    float last_y = floorf(y1);
    float tmp = ceilf(y2 - y1);
    bool cond = fabsf(tmp - dis) > 0.35f * dis;
    if (cond) { dsum += tmp; dnum += 1.0f; dis = dsum / fmaxf(dnum, 1.0f); }
    float start_raw = last_y - 1.8f * dis;
    float end_f   = rintf(start_raw + 1.8f * dis);   // jnp.round = rint
    float start_f = rintf(start_raw);
    int s2 = (int)fmaxf(start_f, 0.0f);
    int e2 = (int)fminf(end_f, (float)(HH - 1));
    bool bvalid = (s2 <= e2) && (end_f >= 0.0f) && (start_f <= (float)(HH - 1));

    M = -INFINITY; Z = 0.0f; SX = 0.0f; SY = 0.0f;
    if (bvalid) merge_partials(F, i * HH, s2, e2, M, Z, SX, SY);  // uniform branch
    finalize2(M, Z, SX, SY, s2, e2, bvalid, ax, ay);
    o[2 * i] = ax; o[2 * i + 1] = ay;
  }

  if (threadIdx.x == 0) {
#pragma unroll
    for (int k = 0; k < 22; ++k) out[k] = o[k];
  }
}

extern "C" void kernel_launch(void* const* d_in, const int* in_sizes, int n_in,
                              void* d_out, int out_size, void* d_ws, size_t ws_size,
                              hipStream_t stream) {
  const float* heat = (const float*)d_in[0];
  float* out = (float*)d_out;
  float4* F = (float4*)d_ws;  // 22528 * 16 B = 360 KB
  hipLaunchKernelGGL(k_partials, dim3(11 * HH / 4), dim3(NB1), 0, stream, heat, F);
  hipLaunchKernelGGL(k_chain, dim3(1), dim3(NT2), 0, stream, F, out);
}

// Round 2
// 243.090 us; speedup vs baseline: 1.0730x; 1.0730x over previous
//
#include <hip/hip_runtime.h>
#include <math.h>

#define HH 2048
#define WW 2048
#define NB 256
#define STAGE_GRID 256

// ---------- wave primitives ----------

__device__ __forceinline__ float wave_fmax(float v) {
#pragma unroll
  for (int m = 1; m < 64; m <<= 1) v = fmaxf(v, __shfl_xor(v, m, 64));
  return v;
}
__device__ __forceinline__ float wave_fsum(float v) {
#pragma unroll
  for (int m = 1; m < 64; m <<= 1) v += __shfl_xor(v, m, 64);
  return v;
}

// ---------- online softmax-partial combine ----------
// (M,Z,SX,SY) <- combine with (m2,z2,sx2,sy2). Handles -inf on either side.
__device__ __forceinline__ void pmerge(float& M, float& Z, float& SX, float& SY,
                                       float m2, float z2, float sx2, float sy2) {
  float Mn = fmaxf(M, m2);
  float wa = (M == Mn) ? 1.0f : expf(M - Mn);    // both -inf -> 1 (Z=0 anyway)
  float wb = (m2 == Mn) ? 1.0f : expf(m2 - Mn);
  Z  = Z * wa + z2 * wb;
  SX = SX * wa + sx2 * wb;
  SY = SY * wa + sy2 * wb;
  M = Mn;
}

// Block-wide online reduce of a per-thread partial; broadcasts result to all
// threads. 2 barriers. Deterministic (same order in every block/thread).
__device__ void block_merge(float4 p, float& M, float& Z, float& SX, float& SY) {
  __shared__ float4 s4[4];
#pragma unroll
  for (int s = 1; s < 64; s <<= 1) {
    float m2 = __shfl_xor(p.x, s, 64);
    float z2 = __shfl_xor(p.y, s, 64);
    float sx2 = __shfl_xor(p.z, s, 64);
    float sy2 = __shfl_xor(p.w, s, 64);
    pmerge(p.x, p.y, p.z, p.w, m2, z2, sx2, sy2);
  }
  __syncthreads();                        // WAR guard across calls
  if ((threadIdx.x & 63) == 0) s4[threadIdx.x >> 6] = p;
  __syncthreads();
  M = -INFINITY; Z = 0.0f; SX = 0.0f; SY = 0.0f;
#pragma unroll
  for (int k = 0; k < 4; ++k) {
    float4 q = s4[k];
    pmerge(M, Z, SX, SY, q.x, q.y, q.z, q.w);
  }
}

// ---------- per-row softmax partial, ONE wave, no barriers ----------
// Returns (M, z, sx): z = sum(exp(100*v - M)), sx = sum(exp * col).
// Kept bit-identical to the verified version (two-phase within the row).
__device__ float4 wave_row_partial(const float* __restrict__ rowp) {
  const int lane = threadIdx.x & 63;
  const float4* r4 = (const float4*)rowp;
  float d[32];
  float m = -INFINITY;
#pragma unroll
  for (int p = 0; p < 8; ++p) {
    float4 v = r4[lane + 64 * p];
    d[4 * p + 0] = v.x * 100.0f;  // BETA
    d[4 * p + 1] = v.y * 100.0f;
    d[4 * p + 2] = v.z * 100.0f;
    d[4 * p + 3] = v.w * 100.0f;
    m = fmaxf(m, fmaxf(fmaxf(d[4 * p], d[4 * p + 1]), fmaxf(d[4 * p + 2], d[4 * p + 3])));
  }
  float M = wave_fmax(m);
  float z = 0.0f, sx = 0.0f;
#pragma unroll
  for (int p = 0; p < 8; ++p) {
    float c0 = (float)(4 * (lane + 64 * p));
#pragma unroll
    for (int k = 0; k < 4; ++k) {
      float e = expf(d[4 * p + k] - M);
      z += e;
      sx += e * (c0 + (float)k);
    }
  }
  z = wave_fsum(z);
  sx = wave_fsum(sx);
  return make_float4(M, z, sx, 0.0f);
}

// Merge per-row partials F[r], r in [s,e] (sy weight = r). Single online pass,
// block-wide, result broadcast to all threads.
__device__ void merge_partials(const float4* __restrict__ F, int s, int e,
                               float& M, float& Z, float& SX, float& SY) {
  float4 a = make_float4(-INFINITY, 0.0f, 0.0f, 0.0f);
  for (int r = s + (int)threadIdx.x; r <= e; r += NB) {
    float4 p = F[r];
    pmerge(a.x, a.y, a.z, a.w, p.x, p.y, p.z, p.y * (float)r);
  }
  block_merge(a, M, Z, SX, SY);
}

// Analytic out-of-band complement (masked elements are exactly 0), then divide.
__device__ void finalize2(float M, float Z, float SX, float SY, int s, int e,
                          bool valid, float& ax, float& ay) {
  int nin = valid ? (e - s + 1) : 0;
  int nout = HH - nin;
  if (nout > 0) {
    float M2 = fmaxf(M, 0.0f);
    float wi = (M == M2) ? 1.0f : expf(M - M2);   // M=-inf -> 0
    float wo = (M2 == 0.0f) ? 1.0f : expf(-M2);   // underflows to 0 for typical M
    Z *= wi; SX *= wi; SY *= wi;
    float nout_e = (float)nout * (float)WW;                                  // exact
    float sox = (float)nout * 2096128.0f;                                    // nout*W(W-1)/2
    float sinr = valid ? (float)(((long)(s + e) * (e - s + 1)) / 2) : 0.0f;  // exact
    float soy = (2096128.0f - sinr) * 2048.0f;                               // exact
    Z  += wo * nout_e;
    SX += wo * sox;
    SY += wo * soy;
  }
  ax = SX / Z;
  ay = SY / Z;
}

// ---------- workspace layout (floats) ----------
// state slots: slot i at ws + 32*i, i in 0..8; each 28 floats:
//   [0..21] out, [22] dis, [23] dsum, [24] dnum, [25] band_s, [26] band_e, [27] valid
// F  at ws+512: 4096 x float4 (ch9 rows 0..2047, ch10 rows 2048..4095)
// B0 at F+4096: 2048 x float4; B1 at B0+2048 (ping-pong band partials, abs-row idx)

// Kernel A: per-wave row partials for channels 9,10. No barriers at all.
__global__ __launch_bounds__(NB) void k_rows910(const float* __restrict__ heat,
                                                float* ws) {
  float4* F = (float4*)(ws + 512);
  int gw = blockIdx.x * 4 + (threadIdx.x >> 6);       // 0..4095
  int ch = 9 + (gw >> 11);
  int r = gw & (HH - 1);
  float4 t = wave_row_partial(heat + ((size_t)ch * HH + r) * WW);
  if ((threadIdx.x & 63) == 0) F[gw] = t;
}

// Stage kernel. i=8: seed from F. i in [0,8): merge prev band. i=-1: final+output.
// Reads state slot i+1, writes state slot i (no same-slot read/write race).
__global__ __launch_bounds__(NB) void k_stage(const float* __restrict__ heat,
                                              float* ws, float* __restrict__ out,
                                              int i) {
  float4* F  = (float4*)(ws + 512);
  float4* B0 = F + 4096;
  float4* B1 = B0 + HH;

  float st[28];
  if (i == 8) {
    for (int k = 0; k < 28; ++k) st[k] = 0.0f;
    float M, Z, SX, SY, ax, ay;
    merge_partials(F, 0, HH - 1, M, Z, SX, SY);
    finalize2(M, Z, SX, SY, 0, HH - 1, true, ax, ay);
    st[18] = ax; st[19] = ay;                                   // out[9]
    merge_partials(F + HH, 0, HH - 1, M, Z, SX, SY);
    finalize2(M, Z, SX, SY, 0, HH - 1, true, ax, ay);
    st[20] = ax; st[21] = ay;                                   // out[10]
    st[22] = st[21] - st[19];                                   // dis0
    st[23] = 0.0f; st[24] = 0.0f;
  } else {
    const float* prev = ws + 32 * (i + 1);
    for (int k = 0; k < 28; ++k) st[k] = prev[k];
    const int j = i + 1;                                        // channel to finish
    const float4* Bprev = (j & 1) ? B1 : B0;
    int s = (int)st[25], e = (int)st[26];
    bool valid = (st[27] != 0.0f);                              // block-uniform
    float M = -INFINITY, Z = 0.0f, SX = 0.0f, SY = 0.0f, ax, ay;
    if (valid) merge_partials(Bprev, s, e, M, Z, SX, SY);
    finalize2(M, Z, SX, SY, s, e, valid, ax, ay);
    st[2 * j] = ax; st[2 * j + 1] = ay;
  }

  if (i >= 0) {
    // Band + dis-state update (all threads compute identically)
    float y1 = st[2 * (i + 1) + 1];
    float y2 = st[2 * (i + 2) + 1];
    float dis = st[22], dsum = st[23], dnum = st[24];
    float last_y = floorf(y1);
    float tmp = ceilf(y2 - y1);
    bool cond = fabsf(tmp - dis) > 0.35f * dis;
    if (cond) { dsum += tmp; dnum += 1.0f; dis = dsum / fmaxf(dnum, 1.0f); }
    float start_raw = last_y - 1.8f * dis;
    float end_f   = rintf(start_raw + 1.8f * dis);   // jnp.round = rint
    float start_f = rintf(start_raw);
    int s2 = (int)fmaxf(start_f, 0.0f);
    int e2 = (int)fminf(end_f, (float)(HH - 1));
    bool bvalid = (s2 <= e2) && (end_f >= 0.0f) && (start_f <= (float)(HH - 1));
    st[22] = dis; st[23] = dsum; st[24] = dnum;
    st[25] = (float)s2; st[26] = (float)e2; st[27] = bvalid ? 1.0f : 0.0f;

    float4* Bcur = (i & 1) ? B1 : B0;
    if (bvalid) {
      const int wid = (int)(blockIdx.x * 4) + (threadIdx.x >> 6);
      for (int r = s2 + wid; r <= e2; r += (int)gridDim.x * 4) {
        float4 t = wave_row_partial(heat + ((size_t)i * HH + r) * WW);
        if ((threadIdx.x & 63) == 0) Bcur[r] = t;
      }
    }
    if (blockIdx.x == 0 && threadIdx.x == 0) {
      float* slot = ws + 32 * i;
      for (int k = 0; k < 28; ++k) slot[k] = st[k];
    }
  } else {
    if (blockIdx.x == 0 && threadIdx.x < 22) out[threadIdx.x] = st[threadIdx.x];
  }
}

extern "C" void kernel_launch(void* const* d_in, const int* in_sizes, int n_in,
                              void* d_out, int out_size, void* d_ws, size_t ws_size,
                              hipStream_t stream) {
  const float* heat = (const float*)d_in[0];
  float* out = (float*)d_out;
  float* ws = (float*)d_ws;
  hipLaunchKernelGGL(k_rows910, dim3(1024), dim3(NB), 0, stream, heat, ws);
  for (int i = 8; i >= 0; --i) {
    hipLaunchKernelGGL(k_stage, dim3(STAGE_GRID), dim3(NB), 0, stream, heat, ws, out, i);
  }
  hipLaunchKernelGGL(k_stage, dim3(1), dim3(NB), 0, stream, heat, ws, out, -1);
}